// Round 8
// baseline (635.666 us; speedup 1.0000x reference)
//
#include <hip/hip_runtime.h>
#include <cmath>

// Problem constants
#define Bn 4
#define Sn 2048
#define En 256
#define Hn 8
#define Dn 32
#define KD 256          // inner GEMM dim (= En)

static constexpr float SCALE_F = 0.17677669529663687f;  // 32^-0.5

// ---------- lengths[b] = sum(mask[b,:]) ----------
__global__ __launch_bounds__(256) void len_kernel(const int* __restrict__ mask,
                                                  int* __restrict__ len) {
  int b = blockIdx.x, t = threadIdx.x;
  int s = 0;
  for (int i = t; i < Sn; i += 256) s += mask[b * Sn + i];
#pragma unroll
  for (int off = 32; off > 0; off >>= 1) s += __shfl_down(s, off, 64);
  __shared__ int red[4];
  if ((t & 63) == 0) red[t >> 6] = s;
  __syncthreads();
  if (t == 0) len[b] = red[0] + red[1] + red[2] + red[3];
}

// ---------- tiled GEMM: C[M,N] = A[M,256] @ W[N,256]^T  (all fp32) ----------
template <int BM, int BN, int TM, int TN, int EPI>
__global__ __launch_bounds__(256) void gemm_k(
    const float* __restrict__ Ap,
    const float* __restrict__ W0,
    const float* __restrict__ W1,
    const float* __restrict__ W2,
    float* __restrict__ O0, float* __restrict__ O1, float* __restrict__ O2,
    float* __restrict__ Oout) {
  constexpr int BK = 32;
  __shared__ __align__(16) float As[BK][BM + 4];
  __shared__ __align__(16) float Bs[BK][BN + 4];
  const int tid = threadIdx.x;
  const int j0 = blockIdx.x * BN;
  const int i0 = blockIdx.y * BM;

  const float* Wp;
  int jc0;
  if constexpr (EPI == 0) {
    const int mat = j0 >> 8;
    Wp = (mat == 0) ? W0 : ((mat == 1) ? W1 : W2);
    jc0 = j0 & 255;
  } else {
    Wp = W0;
    jc0 = j0;
  }

  float acc[TM][TN];
#pragma unroll
  for (int ii = 0; ii < TM; ++ii)
#pragma unroll
    for (int jj = 0; jj < TN; ++jj) acc[ii][jj] = 0.f;

  for (int k0 = 0; k0 < KD; k0 += BK) {
#pragma unroll
    for (int it = 0; it < (BM * BK / 4) / 256; ++it) {
      int c4 = tid + it * 256;
      int row = c4 >> 3, kk4 = (c4 & 7) * 4;
      float4 v = *(const float4*)&Ap[(size_t)(i0 + row) * KD + k0 + kk4];
      As[kk4 + 0][row] = v.x; As[kk4 + 1][row] = v.y;
      As[kk4 + 2][row] = v.z; As[kk4 + 3][row] = v.w;
    }
#pragma unroll
    for (int it = 0; it < (BN * BK / 4) / 256; ++it) {
      int c4 = tid + it * 256;
      int row = c4 >> 3, kk4 = (c4 & 7) * 4;
      float4 v = *(const float4*)&Wp[(size_t)(jc0 + row) * KD + k0 + kk4];
      Bs[kk4 + 0][row] = v.x; Bs[kk4 + 1][row] = v.y;
      Bs[kk4 + 2][row] = v.z; Bs[kk4 + 3][row] = v.w;
    }
    __syncthreads();
    {
      const int tx = tid & 15, ty = tid >> 4;
#pragma unroll
      for (int kk = 0; kk < BK; ++kk) {
        float a[TM], bb[TN];
#pragma unroll
        for (int ii = 0; ii < TM; ++ii) a[ii] = As[kk][ty * TM + ii];
#pragma unroll
        for (int jj = 0; jj < TN; ++jj) bb[jj] = Bs[kk][tx * TN + jj];
#pragma unroll
        for (int ii = 0; ii < TM; ++ii)
#pragma unroll
          for (int jj = 0; jj < TN; ++jj)
            acc[ii][jj] = fmaf(a[ii], bb[jj], acc[ii][jj]);
      }
    }
    __syncthreads();
  }

  const int tx = tid & 15, ty = tid >> 4;
  if constexpr (EPI == 0) {
    const int mat = j0 >> 8;
    float* obase = (mat == 0) ? O0 : ((mat == 1) ? O1 : O2);
    const float scale = (mat == 0) ? SCALE_F : 1.0f;  // fold softmax scale into Q
#pragma unroll
    for (int ii = 0; ii < TM; ++ii) {
      int i = i0 + ty * TM + ii;
      int bb_ = i >> 11, s = i & (Sn - 1);
#pragma unroll
      for (int jj = 0; jj < TN; jj += 4) {
        int c = jc0 + tx * TN + jj;
        int h = c >> 5, d = c & 31;
        float4 v = make_float4(acc[ii][jj] * scale, acc[ii][jj + 1] * scale,
                               acc[ii][jj + 2] * scale, acc[ii][jj + 3] * scale);
        *(float4*)&obase[((size_t)(bb_ * Hn + h) * Sn + s) * Dn + d] = v;
      }
    }
  } else {
#pragma unroll
    for (int ii = 0; ii < TM; ++ii) {
      int i = i0 + ty * TM + ii;
#pragma unroll
      for (int jj = 0; jj < TN; jj += 4) {
        int j = j0 + tx * TN + jj;
        float4 v = make_float4(acc[ii][jj], acc[ii][jj + 1],
                               acc[ii][jj + 2], acc[ii][jj + 3]);
        *(float4*)&Oout[(size_t)i * En + j] = v;
      }
    }
  }
}

// ---------- flash attention: wave = 8 queries x 8 key-octets; 16 waves/block ----------
// Block = 1024 thr = 16 waves = 128 queries sharing each staged K/V tile (R6-level reuse).
// lane (ql, ko): private (m,l,acc[32]) over keys {ko + 8j}; shfl-butterfly merge at end.
// pacc[((b*H+h)*NS+split)*Sn + q][32], pml[...][2] = (m,l)
template <int NS>
__global__ __launch_bounds__(1024, 4) void attn_kernel(
    const float* __restrict__ Qg, const float* __restrict__ Kg,
    const float* __restrict__ Vg, const int* __restrict__ len,
    float* __restrict__ pacc, float* __restrict__ pml) {
  const int split = blockIdx.x & (NS - 1);
  const int qg = blockIdx.x / NS;
  const int h = blockIdx.y, b = blockIdx.z;
  const int L = len[b];
  const int q0 = qg * 128;
  if (q0 >= L) return;                 // block-uniform exit
  const int chunk = ((L + NS * 64 - 1) / (NS * 64)) * 64;
  const int ks = split * chunk;
  if (ks >= L) return;
  const int ke = min(L, ks + chunk);

  const int tid = threadIdx.x;
  const int lane = tid & 63;
  const int wv = tid >> 6;             // wave 0..15
  const int ql = lane >> 3;            // query-in-wave 0..7
  const int ko = lane & 7;             // key octet 0..7
  const int q = q0 + wv * 8 + ql;      // < Sn always; masked vs L at store
  const size_t bh = (size_t)(b * Hn + h) * Sn;

  float qr[32];
  {
    const float4* qp = (const float4*)&Qg[(bh + q) * Dn];
#pragma unroll
    for (int i = 0; i < 8; ++i) {
      float4 v = qp[i];
      qr[i * 4 + 0] = v.x; qr[i * 4 + 1] = v.y;
      qr[i * 4 + 2] = v.z; qr[i * 4 + 3] = v.w;
    }
  }

  __shared__ __align__(16) float Kld[64][36];  // stride 36: conflict-free octet reads
  __shared__ __align__(16) float Vld[64][36];

  float m = -1.0e30f, l = 0.f;
  float acc[32];
#pragma unroll
  for (int d = 0; d < 32; ++d) acc[d] = 0.f;

  for (int k0 = ks; k0 < ke; k0 += 64) {
    const int nk = min(64, ke - k0);
    __syncthreads();
    {  // 1024 threads stage 64x32 K and V tiles: exactly one float4 each
      const int arr = tid >> 9;        // 0=K, 1=V (wave-uniform)
      const int f4 = tid & 511;
      const int row = f4 >> 3, c4 = (f4 & 7) * 4;
      float4 v = make_float4(0.f, 0.f, 0.f, 0.f);
      if (row < nk) {
        const float* src = arr ? Vg : Kg;
        v = *(const float4*)&src[(bh + k0 + row) * Dn + c4];
      }
      float* dst = arr ? &Vld[row][c4] : &Kld[row][c4];
      *(float4*)dst = v;               // zero-fill tail rows: no stale data
    }
    __syncthreads();

    // this lane's 8 keys: rows ko + 8j
    float s[8];
#pragma unroll
    for (int j = 0; j < 8; ++j) s[j] = 0.f;
#pragma unroll
    for (int i = 0; i < 8; ++i) {
      const float qx = qr[i * 4 + 0], qy = qr[i * 4 + 1];
      const float qz = qr[i * 4 + 2], qw = qr[i * 4 + 3];
#pragma unroll
      for (int j = 0; j < 8; ++j) {
        float4 kv = *(const float4*)&Kld[ko + 8 * j][i * 4];
        s[j] = fmaf(qx, kv.x, s[j]);
        s[j] = fmaf(qy, kv.y, s[j]);
        s[j] = fmaf(qz, kv.z, s[j]);
        s[j] = fmaf(qw, kv.w, s[j]);
      }
    }
#pragma unroll
    for (int j = 0; j < 8; ++j)
      if (ko + 8 * j >= nk) s[j] = -3.0e38f;   // masked key

    float m01 = fmaxf(s[0], s[1]), m23 = fmaxf(s[2], s[3]);
    float m45 = fmaxf(s[4], s[5]), m67 = fmaxf(s[6], s[7]);
    float m8 = fmaxf(fmaxf(m01, m23), fmaxf(m45, m67));
    float nm = fmaxf(m, m8);
    float p[8];
#pragma unroll
    for (int j = 0; j < 8; ++j) p[j] = __expf(s[j] - nm);  // masked -> 0
    float sc = __expf(m - nm);
    float psum = ((p[0] + p[1]) + (p[2] + p[3])) + ((p[4] + p[5]) + (p[6] + p[7]));
    l = l * sc + psum;
    m = nm;
#pragma unroll
    for (int i = 0; i < 8; ++i) {
      float ax = acc[i * 4 + 0] * sc, ay = acc[i * 4 + 1] * sc;
      float az = acc[i * 4 + 2] * sc, aw = acc[i * 4 + 3] * sc;
#pragma unroll
      for (int j = 0; j < 8; ++j) {
        float4 vv = *(const float4*)&Vld[ko + 8 * j][i * 4];
        ax = fmaf(p[j], vv.x, ax);
        ay = fmaf(p[j], vv.y, ay);
        az = fmaf(p[j], vv.z, az);
        aw = fmaf(p[j], vv.w, aw);
      }
      acc[i * 4 + 0] = ax; acc[i * 4 + 1] = ay;
      acc[i * 4 + 2] = az; acc[i * 4 + 3] = aw;
    }
  }

  // ---- merge 8 key-octets within each query group (lane bits 0..2) ----
#pragma unroll
  for (int mask = 1; mask <= 4; mask <<= 1) {
    float mo = __shfl_xor(m, mask, 64);
    float lo = __shfl_xor(l, mask, 64);
    float nm = fmaxf(m, mo);
    float sa = __expf(m - nm);
    float sb = __expf(mo - nm);
    l = l * sa + lo * sb;
#pragma unroll
    for (int d = 0; d < 32; ++d) {
      float ao = __shfl_xor(acc[d], mask, 64);
      acc[d] = acc[d] * sa + ao * sb;
    }
    m = nm;
  }

  if (q < L) {
    const size_t idx = ((size_t)(b * Hn + h) * NS + split) * Sn + q;
    // lane ko writes float4 chunk #ko of the 32-float acc (coalesced 128B per query)
    float4 v = make_float4(acc[0], acc[1], acc[2], acc[3]);
#pragma unroll
    for (int i = 1; i < 8; ++i)
      if (ko == i) v = make_float4(acc[4 * i], acc[4 * i + 1],
                                   acc[4 * i + 2], acc[4 * i + 3]);
    *(float4*)&pacc[idx * 32 + ko * 4] = v;
    if (ko == 0) *(float2*)&pml[idx * 2] = make_float2(m, l);
  }
}

// ---------- merge key-splits, write scrambled P: P[b].flat[h*L*D + q*D + d] ----------
template <int NS>
__global__ __launch_bounds__(256) void combine_kernel(const float* __restrict__ pacc,
                                                      const float* __restrict__ pml,
                                                      const int* __restrict__ len,
                                                      float* __restrict__ P) {
  const int h = blockIdx.y, b = blockIdx.z;
  const int L = len[b];
  const int q = blockIdx.x * 256 + threadIdx.x;
  if (q >= L) return;
  const int chunk = ((L + NS * 64 - 1) / (NS * 64)) * 64;
  const size_t base = (size_t)(b * Hn + h) * NS * Sn;

  float M = -INFINITY;
  int ns = 0;
  float ms[NS], ls[NS];
#pragma unroll
  for (int sp = 0; sp < NS; ++sp) {
    if (sp * chunk < L) {
      float2 ml = *(const float2*)&pml[(base + (size_t)sp * Sn + q) * 2];
      ms[sp] = ml.x; ls[sp] = ml.y;
      M = fmaxf(M, ml.x);
      ns = sp + 1;
    }
  }
  float T = 0.f;
  float o[32];
#pragma unroll
  for (int d = 0; d < 32; ++d) o[d] = 0.f;
  for (int sp = 0; sp < ns; ++sp) {
    float w = __expf(ms[sp] - M);
    T += ls[sp] * w;
    const float4* pp = (const float4*)&pacc[(base + (size_t)sp * Sn + q) * 32];
#pragma unroll
    for (int i = 0; i < 8; ++i) {
      float4 v = pp[i];
      o[i * 4 + 0] = fmaf(w, v.x, o[i * 4 + 0]);
      o[i * 4 + 1] = fmaf(w, v.y, o[i * 4 + 1]);
      o[i * 4 + 2] = fmaf(w, v.z, o[i * 4 + 2]);
      o[i * 4 + 3] = fmaf(w, v.w, o[i * 4 + 3]);
    }
  }
  const float inv = 1.0f / T;
  float* dst = &P[(size_t)b * Sn * En + (size_t)h * L * Dn + (size_t)q * Dn];
#pragma unroll
  for (int i = 0; i < 8; ++i) {
    float4 v = make_float4(o[i * 4] * inv, o[i * 4 + 1] * inv,
                           o[i * 4 + 2] * inv, o[i * 4 + 3] * inv);
    *(float4*)&dst[i * 4] = v;
  }
}

// ---------- zero P tail [L*E, S*E) per batch ----------
__global__ __launch_bounds__(256) void ztail_kernel(const int* __restrict__ len,
                                                    float* __restrict__ P) {
  const int b = blockIdx.y;
  const int L = len[b];
  const int idx = (blockIdx.x * 256 + threadIdx.x) * 4;
  if (idx >= L * En)
    *(float4*)&P[(size_t)b * Sn * En + idx] = make_float4(0.f, 0.f, 0.f, 0.f);
}

extern "C" void kernel_launch(void* const* d_in, const int* in_sizes, int n_in,
                              void* d_out, int out_size, void* d_ws, size_t ws_size,
                              hipStream_t stream) {
  (void)in_sizes; (void)n_in; (void)out_size; (void)ws_size;
  const float* x  = (const float*)d_in[0];  // fp32 (B,S,E)
  const int* mask = (const int*)d_in[1];    // int32 (B,S)
  const float* Wq = (const float*)d_in[2];  // fp32 (E,E)
  const float* Wk = (const float*)d_in[3];
  const float* Wv = (const float*)d_in[4];
  const float* Wo = (const float*)d_in[5];
  float* out = (float*)d_out;               // fp32 (B,S,E)

  // workspace (fp32): lengths | Q | K | V | P | pacc | pml  (~69 MB; ws is ~262 MB)
  float* wsf = (float*)d_ws;
  int* lengths = (int*)d_ws;
  const size_t BHSD = (size_t)Bn * Hn * Sn * Dn;  // 2,097,152
  float* Qw = wsf + 64;
  float* Kw = Qw + BHSD;
  float* Vw = Kw + BHSD;
  float* Pw = Vw + BHSD;
  float* pacc = Pw + (size_t)Bn * Sn * En;
  constexpr int NS = 4;
  float* pml = pacc + (size_t)Bn * Hn * NS * Sn * 32;

  len_kernel<<<dim3(Bn), 256, 0, stream>>>(mask, lengths);
  gemm_k<128, 128, 8, 8, 0><<<dim3(6, 64), 256, 0, stream>>>(
      x, Wq, Wk, Wv, Qw, Kw, Vw, nullptr);
  attn_kernel<NS><<<dim3((Sn / 128) * NS, Hn, Bn), 1024, 0, stream>>>(
      Qw, Kw, Vw, lengths, pacc, pml);
  combine_kernel<NS><<<dim3(Sn / 256, Hn, Bn), 256, 0, stream>>>(
      pacc, pml, lengths, Pw);
  ztail_kernel<<<dim3(Sn * En / 1024, Bn), 256, 0, stream>>>(lengths, Pw);
  gemm_k<64, 128, 4, 8, 1><<<dim3(2, 128), 256, 0, stream>>>(
      Pw, Wo, Wo, Wo, nullptr, nullptr, nullptr, out);
}

// Round 9
// 426.047 us; speedup vs baseline: 1.4920x; 1.4920x over previous
//
#include <hip/hip_runtime.h>
#include <cmath>

// Problem constants
#define Bn 4
#define Sn 2048
#define En 256
#define Hn 8
#define Dn 32
#define KD 256          // inner GEMM dim (= En)
#define NS 8            // max key splits
#define CHUNK 256       // constant keys per split -> uniform block durations

static constexpr float SCALE_F = 0.17677669529663687f;  // 32^-0.5

// ---------- lengths[b] = sum(mask[b,:]) ----------
__global__ __launch_bounds__(256) void len_kernel(const int* __restrict__ mask,
                                                  int* __restrict__ len) {
  int b = blockIdx.x, t = threadIdx.x;
  int s = 0;
  for (int i = t; i < Sn; i += 256) s += mask[b * Sn + i];
#pragma unroll
  for (int off = 32; off > 0; off >>= 1) s += __shfl_down(s, off, 64);
  __shared__ int red[4];
  if ((t & 63) == 0) red[t >> 6] = s;
  __syncthreads();
  if (t == 0) len[b] = red[0] + red[1] + red[2] + red[3];
}

// ---------- tiled GEMM: C[M,N] = A[M,256] @ W[N,256]^T  (all fp32) ----------
template <int BM, int BN, int TM, int TN, int EPI>
__global__ __launch_bounds__(256) void gemm_k(
    const float* __restrict__ Ap,
    const float* __restrict__ W0,
    const float* __restrict__ W1,
    const float* __restrict__ W2,
    float* __restrict__ O0, float* __restrict__ O1, float* __restrict__ O2,
    float* __restrict__ Oout) {
  constexpr int BK = 32;
  __shared__ __align__(16) float As[BK][BM + 4];
  __shared__ __align__(16) float Bs[BK][BN + 4];
  const int tid = threadIdx.x;
  const int j0 = blockIdx.x * BN;
  const int i0 = blockIdx.y * BM;

  const float* Wp;
  int jc0;
  if constexpr (EPI == 0) {
    const int mat = j0 >> 8;
    Wp = (mat == 0) ? W0 : ((mat == 1) ? W1 : W2);
    jc0 = j0 & 255;
  } else {
    Wp = W0;
    jc0 = j0;
  }

  float acc[TM][TN];
#pragma unroll
  for (int ii = 0; ii < TM; ++ii)
#pragma unroll
    for (int jj = 0; jj < TN; ++jj) acc[ii][jj] = 0.f;

  for (int k0 = 0; k0 < KD; k0 += BK) {
#pragma unroll
    for (int it = 0; it < (BM * BK / 4) / 256; ++it) {
      int c4 = tid + it * 256;
      int row = c4 >> 3, kk4 = (c4 & 7) * 4;
      float4 v = *(const float4*)&Ap[(size_t)(i0 + row) * KD + k0 + kk4];
      As[kk4 + 0][row] = v.x; As[kk4 + 1][row] = v.y;
      As[kk4 + 2][row] = v.z; As[kk4 + 3][row] = v.w;
    }
#pragma unroll
    for (int it = 0; it < (BN * BK / 4) / 256; ++it) {
      int c4 = tid + it * 256;
      int row = c4 >> 3, kk4 = (c4 & 7) * 4;
      float4 v = *(const float4*)&Wp[(size_t)(jc0 + row) * KD + k0 + kk4];
      Bs[kk4 + 0][row] = v.x; Bs[kk4 + 1][row] = v.y;
      Bs[kk4 + 2][row] = v.z; Bs[kk4 + 3][row] = v.w;
    }
    __syncthreads();
    {
      const int tx = tid & 15, ty = tid >> 4;
#pragma unroll
      for (int kk = 0; kk < BK; ++kk) {
        float a[TM], bb[TN];
#pragma unroll
        for (int ii = 0; ii < TM; ++ii) a[ii] = As[kk][ty * TM + ii];
#pragma unroll
        for (int jj = 0; jj < TN; ++jj) bb[jj] = Bs[kk][tx * TN + jj];
#pragma unroll
        for (int ii = 0; ii < TM; ++ii)
#pragma unroll
          for (int jj = 0; jj < TN; ++jj)
            acc[ii][jj] = fmaf(a[ii], bb[jj], acc[ii][jj]);
      }
    }
    __syncthreads();
  }

  const int tx = tid & 15, ty = tid >> 4;
  if constexpr (EPI == 0) {
    const int mat = j0 >> 8;
    float* obase = (mat == 0) ? O0 : ((mat == 1) ? O1 : O2);
    const float scale = (mat == 0) ? SCALE_F : 1.0f;  // fold softmax scale into Q
#pragma unroll
    for (int ii = 0; ii < TM; ++ii) {
      int i = i0 + ty * TM + ii;
      int bb_ = i >> 11, s = i & (Sn - 1);
#pragma unroll
      for (int jj = 0; jj < TN; jj += 4) {
        int c = jc0 + tx * TN + jj;
        int h = c >> 5, d = c & 31;
        float4 v = make_float4(acc[ii][jj] * scale, acc[ii][jj + 1] * scale,
                               acc[ii][jj + 2] * scale, acc[ii][jj + 3] * scale);
        *(float4*)&obase[((size_t)(bb_ * Hn + h) * Sn + s) * Dn + d] = v;
      }
    }
  } else {
#pragma unroll
    for (int ii = 0; ii < TM; ++ii) {
      int i = i0 + ty * TM + ii;
#pragma unroll
      for (int jj = 0; jj < TN; jj += 4) {
        int j = j0 + tx * TN + jj;
        float4 v = make_float4(acc[ii][jj], acc[ii][jj + 1],
                               acc[ii][jj + 2], acc[ii][jj + 3]);
        *(float4*)&Oout[(size_t)i * En + j] = v;
      }
    }
  }
}

// ---------- flash attention, thread-per-query, constant 256-key splits ----------
// R6 structure (proven 25 MB FETCH via bh-clustered dispatch + 128q/block reuse),
// with CONSTANT chunk so all active blocks have equal duration (no stragglers).
// pacc[((b*H+h)*NS+split)*Sn + q][32], pml[...][2] = (m,l)
__global__ __launch_bounds__(128) void attn_kernel(
    const float* __restrict__ Qg, const float* __restrict__ Kg,
    const float* __restrict__ Vg, const int* __restrict__ len,
    float* __restrict__ pacc, float* __restrict__ pml) {
  const int split = blockIdx.x & (NS - 1);
  const int qblk = blockIdx.x >> 3;    // log2(NS)
  const int h = blockIdx.y, b = blockIdx.z;
  const int L = len[b];
  const int q0 = qblk * 128;
  if (q0 >= L) return;                 // block-uniform exit
  const int ks = split * CHUNK;
  if (ks >= L) return;                 // inactive split for this batch
  const int ke = min(L, ks + CHUNK);

  const int t = threadIdx.x;
  const int q = q0 + t;
  const bool active = q < L;
  const size_t bh = (size_t)(b * Hn + h) * Sn;

  float qr[32];
  if (active) {
    const float4* qp = (const float4*)&Qg[(bh + q) * Dn];
#pragma unroll
    for (int i = 0; i < 8; ++i) {
      float4 v = qp[i];
      qr[i * 4 + 0] = v.x; qr[i * 4 + 1] = v.y;
      qr[i * 4 + 2] = v.z; qr[i * 4 + 3] = v.w;
    }
  } else {
#pragma unroll
    for (int d = 0; d < 32; ++d) qr[d] = 0.f;
  }

  __shared__ __align__(16) float Kld[64][36];
  __shared__ __align__(16) float Vld[64][36];

  float m = -INFINITY, l = 0.f;
  float acc[32];
#pragma unroll
  for (int d = 0; d < 32; ++d) acc[d] = 0.f;

  for (int k0 = ks; k0 < ke; k0 += 64) {
    const int nk = min(64, ke - k0);
    __syncthreads();
#pragma unroll
    for (int it = 0; it < 4; ++it) {
      int f4 = t + it * 128;
      int row = f4 >> 3, c4 = (f4 & 7) * 4;
      if (row < nk) {
        *(float4*)&Kld[row][c4] = *(const float4*)&Kg[(bh + k0 + row) * Dn + c4];
        *(float4*)&Vld[row][c4] = *(const float4*)&Vg[(bh + k0 + row) * Dn + c4];
      }
    }
    __syncthreads();

    int kk = 0;
    // ---- groups of 8 keys: 8 independent score chains, 1 rescale per group ----
    for (; kk + 8 <= nk; kk += 8) {
      float s[8];
#pragma unroll
      for (int j = 0; j < 8; ++j) s[j] = 0.f;
#pragma unroll
      for (int i = 0; i < 8; ++i) {      // dim chunk (float4)
        const float qx = qr[i * 4 + 0], qy = qr[i * 4 + 1];
        const float qz = qr[i * 4 + 2], qw = qr[i * 4 + 3];
#pragma unroll
        for (int j = 0; j < 8; ++j) {
          float4 kv = *(const float4*)&Kld[kk + j][i * 4];
          s[j] = fmaf(qx, kv.x, s[j]);
          s[j] = fmaf(qy, kv.y, s[j]);
          s[j] = fmaf(qz, kv.z, s[j]);
          s[j] = fmaf(qw, kv.w, s[j]);
        }
      }
      float m01 = fmaxf(s[0], s[1]), m23 = fmaxf(s[2], s[3]);
      float m45 = fmaxf(s[4], s[5]), m67 = fmaxf(s[6], s[7]);
      float m8 = fmaxf(fmaxf(m01, m23), fmaxf(m45, m67));
      float nm = fmaxf(m, m8);
      float p[8];
#pragma unroll
      for (int j = 0; j < 8; ++j) p[j] = __expf(s[j] - nm);
      float sc = __expf(m - nm);
      float psum = ((p[0] + p[1]) + (p[2] + p[3])) + ((p[4] + p[5]) + (p[6] + p[7]));
      l = l * sc + psum;
      m = nm;
#pragma unroll
      for (int i = 0; i < 8; ++i) {      // dim chunk
        float ax = acc[i * 4 + 0] * sc, ay = acc[i * 4 + 1] * sc;
        float az = acc[i * 4 + 2] * sc, aw = acc[i * 4 + 3] * sc;
#pragma unroll
        for (int j = 0; j < 8; ++j) {
          float4 vv = *(const float4*)&Vld[kk + j][i * 4];
          ax = fmaf(p[j], vv.x, ax);
          ay = fmaf(p[j], vv.y, ay);
          az = fmaf(p[j], vv.z, az);
          aw = fmaf(p[j], vv.w, aw);
        }
        acc[i * 4 + 0] = ax; acc[i * 4 + 1] = ay;
        acc[i * 4 + 2] = az; acc[i * 4 + 3] = aw;
      }
    }
    // ---- remainder keys (last tile only) ----
    for (; kk < nk; ++kk) {
      const float4* kp = (const float4*)&Kld[kk][0];
      float s0 = 0.f, s1 = 0.f, s2 = 0.f, s3 = 0.f;
#pragma unroll
      for (int i = 0; i < 8; ++i) {
        float4 kv = kp[i];
        s0 = fmaf(qr[i * 4 + 0], kv.x, s0);
        s1 = fmaf(qr[i * 4 + 1], kv.y, s1);
        s2 = fmaf(qr[i * 4 + 2], kv.z, s2);
        s3 = fmaf(qr[i * 4 + 3], kv.w, s3);
      }
      float s = (s0 + s1) + (s2 + s3);
      float nm = fmaxf(m, s);
      float p = __expf(s - nm);
      float sc = __expf(m - nm);
      l = l * sc + p;
      const float4* vp = (const float4*)&Vld[kk][0];
#pragma unroll
      for (int i = 0; i < 8; ++i) {
        float4 vv = vp[i];
        acc[i * 4 + 0] = fmaf(acc[i * 4 + 0], sc, p * vv.x);
        acc[i * 4 + 1] = fmaf(acc[i * 4 + 1], sc, p * vv.y);
        acc[i * 4 + 2] = fmaf(acc[i * 4 + 2], sc, p * vv.z);
        acc[i * 4 + 3] = fmaf(acc[i * 4 + 3], sc, p * vv.w);
      }
      m = nm;
    }
  }
  if (active) {
    const size_t idx = ((size_t)(b * Hn + h) * NS + split) * Sn + q;
    float* pp = &pacc[idx * 32];
#pragma unroll
    for (int i = 0; i < 8; ++i) {
      float4 v = make_float4(acc[i * 4], acc[i * 4 + 1], acc[i * 4 + 2], acc[i * 4 + 3]);
      *(float4*)&pp[i * 4] = v;
    }
    *(float2*)&pml[idx * 2] = make_float2(m, l);
  }
}

// ---------- merge key-splits, write scrambled P: P[b].flat[h*L*D + q*D + d] ----------
__global__ __launch_bounds__(256) void combine_kernel(const float* __restrict__ pacc,
                                                      const float* __restrict__ pml,
                                                      const int* __restrict__ len,
                                                      float* __restrict__ P) {
  const int h = blockIdx.y, b = blockIdx.z;
  const int L = len[b];
  const int q = blockIdx.x * 256 + threadIdx.x;
  if (q >= L) return;
  const size_t base = (size_t)(b * Hn + h) * NS * Sn;

  float M = -INFINITY;
  int ns = 0;
  float ms[NS], ls[NS];
#pragma unroll
  for (int sp = 0; sp < NS; ++sp) {
    if (sp * CHUNK < L) {
      float2 ml = *(const float2*)&pml[(base + (size_t)sp * Sn + q) * 2];
      ms[sp] = ml.x; ls[sp] = ml.y;
      M = fmaxf(M, ml.x);
      ns = sp + 1;
    }
  }
  float T = 0.f;
  float o[32];
#pragma unroll
  for (int d = 0; d < 32; ++d) o[d] = 0.f;
  for (int sp = 0; sp < ns; ++sp) {
    float w = __expf(ms[sp] - M);
    T += ls[sp] * w;
    const float4* pp = (const float4*)&pacc[(base + (size_t)sp * Sn + q) * 32];
#pragma unroll
    for (int i = 0; i < 8; ++i) {
      float4 v = pp[i];
      o[i * 4 + 0] = fmaf(w, v.x, o[i * 4 + 0]);
      o[i * 4 + 1] = fmaf(w, v.y, o[i * 4 + 1]);
      o[i * 4 + 2] = fmaf(w, v.z, o[i * 4 + 2]);
      o[i * 4 + 3] = fmaf(w, v.w, o[i * 4 + 3]);
    }
  }
  const float inv = 1.0f / T;
  float* dst = &P[(size_t)b * Sn * En + (size_t)h * L * Dn + (size_t)q * Dn];
#pragma unroll
  for (int i = 0; i < 8; ++i) {
    float4 v = make_float4(o[i * 4] * inv, o[i * 4 + 1] * inv,
                           o[i * 4 + 2] * inv, o[i * 4 + 3] * inv);
    *(float4*)&dst[i * 4] = v;
  }
}

// ---------- zero P tail [L*E, S*E) per batch ----------
__global__ __launch_bounds__(256) void ztail_kernel(const int* __restrict__ len,
                                                    float* __restrict__ P) {
  const int b = blockIdx.y;
  const int L = len[b];
  const int idx = (blockIdx.x * 256 + threadIdx.x) * 4;
  if (idx >= L * En)
    *(float4*)&P[(size_t)b * Sn * En + idx] = make_float4(0.f, 0.f, 0.f, 0.f);
}

extern "C" void kernel_launch(void* const* d_in, const int* in_sizes, int n_in,
                              void* d_out, int out_size, void* d_ws, size_t ws_size,
                              hipStream_t stream) {
  (void)in_sizes; (void)n_in; (void)out_size; (void)ws_size;
  const float* x  = (const float*)d_in[0];  // fp32 (B,S,E)
  const int* mask = (const int*)d_in[1];    // int32 (B,S)
  const float* Wq = (const float*)d_in[2];  // fp32 (E,E)
  const float* Wk = (const float*)d_in[3];
  const float* Wv = (const float*)d_in[4];
  const float* Wo = (const float*)d_in[5];
  float* out = (float*)d_out;               // fp32 (B,S,E)

  // workspace (fp32): lengths | Q | K | V | P | pacc | pml  (~105 MB; ws ~262 MB)
  float* wsf = (float*)d_ws;
  int* lengths = (int*)d_ws;
  const size_t BHSD = (size_t)Bn * Hn * Sn * Dn;  // 2,097,152
  float* Qw = wsf + 64;
  float* Kw = Qw + BHSD;
  float* Vw = Kw + BHSD;
  float* Pw = Vw + BHSD;
  float* pacc = Pw + (size_t)Bn * Sn * En;
  float* pml = pacc + (size_t)Bn * Hn * NS * Sn * 32;

  len_kernel<<<dim3(Bn), 256, 0, stream>>>(mask, lengths);
  gemm_k<128, 128, 8, 8, 0><<<dim3(6, 64), 256, 0, stream>>>(
      x, Wq, Wk, Wv, Qw, Kw, Vw, nullptr);
  attn_kernel<<<dim3((Sn / 128) * NS, Hn, Bn), 128, 0, stream>>>(
      Qw, Kw, Vw, lengths, pacc, pml);
  combine_kernel<<<dim3(Sn / 256, Hn, Bn), 256, 0, stream>>>(
      pacc, pml, lengths, Pw);
  ztail_kernel<<<dim3(Sn * En / 1024, Bn), 256, 0, stream>>>(lengths, Pw);
  gemm_k<64, 128, 4, 8, 1><<<dim3(2, 128), 256, 0, stream>>>(
      Pw, Wo, Wo, Wo, nullptr, nullptr, nullptr, out);
}

// Round 11
// 282.568 us; speedup vs baseline: 2.2496x; 1.5078x over previous
//
#include <hip/hip_runtime.h>
#include <cmath>

// Problem constants
#define Bn 4
#define Sn 2048
#define En 256
#define Hn 8
#define Dn 32
#define KD 256          // inner GEMM dim (= En)
#define NS 4            // key splits for attention
#define CHUNK 512       // keys per split

static constexpr float SCALE_F = 0.17677669529663687f;  // 32^-0.5

typedef _Float16 half4_t __attribute__((ext_vector_type(4)));
typedef _Float16 half8_t __attribute__((ext_vector_type(8)));
typedef float float4_t __attribute__((ext_vector_type(4)));

// ---------- lengths[b] = sum(mask[b,:]) ----------
__global__ __launch_bounds__(256) void len_kernel(const int* __restrict__ mask,
                                                  int* __restrict__ len) {
  int b = blockIdx.x, t = threadIdx.x;
  int s = 0;
  for (int i = t; i < Sn; i += 256) s += mask[b * Sn + i];
#pragma unroll
  for (int off = 32; off > 0; off >>= 1) s += __shfl_down(s, off, 64);
  __shared__ int red[4];
  if ((t & 63) == 0) red[t >> 6] = s;
  __syncthreads();
  if (t == 0) len[b] = red[0] + red[1] + red[2] + red[3];
}

// ---------- tiled GEMM: C[M,N] = A[M,256] @ W[N,256]^T  (fp32 in) ----------
// EPI==0: writes f16 Qh (scaled), Kh row-major (B,H,S,D); Vt transposed (B,H,D,S)
// EPI==1: A = P (fp32 scrambled), W0 = Wo; fp32 d_out
template <int BM, int BN, int TM, int TN, int EPI>
__global__ __launch_bounds__(256) void gemm_k(
    const float* __restrict__ Ap,
    const float* __restrict__ W0,
    const float* __restrict__ W1,
    const float* __restrict__ W2,
    _Float16* __restrict__ Qh, _Float16* __restrict__ Kh, _Float16* __restrict__ Vt,
    float* __restrict__ Oout) {
  constexpr int BK = 32;
  __shared__ __align__(16) float As[BK][BM + 4];
  __shared__ __align__(16) float Bs[BK][BN + 4];
  const int tid = threadIdx.x;
  const int j0 = blockIdx.x * BN;
  const int i0 = blockIdx.y * BM;

  const float* Wp;
  int jc0;
  if constexpr (EPI == 0) {
    const int mat = j0 >> 8;
    Wp = (mat == 0) ? W0 : ((mat == 1) ? W1 : W2);
    jc0 = j0 & 255;
  } else {
    Wp = W0;
    jc0 = j0;
  }

  float acc[TM][TN];
#pragma unroll
  for (int ii = 0; ii < TM; ++ii)
#pragma unroll
    for (int jj = 0; jj < TN; ++jj) acc[ii][jj] = 0.f;

  for (int k0 = 0; k0 < KD; k0 += BK) {
#pragma unroll
    for (int it = 0; it < (BM * BK / 4) / 256; ++it) {
      int c4 = tid + it * 256;
      int row = c4 >> 3, kk4 = (c4 & 7) * 4;
      float4 v = *(const float4*)&Ap[(size_t)(i0 + row) * KD + k0 + kk4];
      As[kk4 + 0][row] = v.x; As[kk4 + 1][row] = v.y;
      As[kk4 + 2][row] = v.z; As[kk4 + 3][row] = v.w;
    }
#pragma unroll
    for (int it = 0; it < (BN * BK / 4) / 256; ++it) {
      int c4 = tid + it * 256;
      int row = c4 >> 3, kk4 = (c4 & 7) * 4;
      float4 v = *(const float4*)&Wp[(size_t)(jc0 + row) * KD + k0 + kk4];
      Bs[kk4 + 0][row] = v.x; Bs[kk4 + 1][row] = v.y;
      Bs[kk4 + 2][row] = v.z; Bs[kk4 + 3][row] = v.w;
    }
    __syncthreads();
    {
      const int tx = tid & 15, ty = tid >> 4;
#pragma unroll
      for (int kk = 0; kk < BK; ++kk) {
        float a[TM], bb[TN];
#pragma unroll
        for (int ii = 0; ii < TM; ++ii) a[ii] = As[kk][ty * TM + ii];
#pragma unroll
        for (int jj = 0; jj < TN; ++jj) bb[jj] = Bs[kk][tx * TN + jj];
#pragma unroll
        for (int ii = 0; ii < TM; ++ii)
#pragma unroll
          for (int jj = 0; jj < TN; ++jj)
            acc[ii][jj] = fmaf(a[ii], bb[jj], acc[ii][jj]);
      }
    }
    __syncthreads();
  }

  const int tx = tid & 15, ty = tid >> 4;
  if constexpr (EPI == 0) {
    const int mat = j0 >> 8;
    const float scale = (mat == 0) ? SCALE_F : 1.0f;  // fold softmax scale into Q
#pragma unroll
    for (int ii = 0; ii < TM; ++ii) {
      int i = i0 + ty * TM + ii;
      int bb_ = i >> 11, s = i & (Sn - 1);
#pragma unroll
      for (int jj = 0; jj < TN; jj += 4) {
        int c = jc0 + tx * TN + jj;   // 4-aligned -> same head
        int h = c >> 5, d = c & 31;
        if (mat == 2) {               // V transposed: Vt[(bh*32+d)][s]
#pragma unroll
          for (int t2 = 0; t2 < 4; ++t2)
            Vt[((size_t)(bb_ * Hn + h) * Dn + d + t2) * Sn + s] =
                (_Float16)acc[ii][jj + t2];
        } else {
          _Float16* dstH = (mat == 0) ? Qh : Kh;
          half4_t hv;
          hv[0] = (_Float16)(acc[ii][jj + 0] * scale);
          hv[1] = (_Float16)(acc[ii][jj + 1] * scale);
          hv[2] = (_Float16)(acc[ii][jj + 2] * scale);
          hv[3] = (_Float16)(acc[ii][jj + 3] * scale);
          *(half4_t*)&dstH[((size_t)(bb_ * Hn + h) * Sn + s) * Dn + d] = hv;
        }
      }
    }
  } else {
#pragma unroll
    for (int ii = 0; ii < TM; ++ii) {
      int i = i0 + ty * TM + ii;
#pragma unroll
      for (int jj = 0; jj < TN; jj += 4) {
        int j = j0 + tx * TN + jj;
        float4 v = make_float4(acc[ii][jj], acc[ii][jj + 1],
                               acc[ii][jj + 2], acc[ii][jj + 3]);
        *(float4*)&Oout[(size_t)i * En + j] = v;
      }
    }
  }
}

// ---------- MFMA flash attention: wave = 16 queries, 16-key steps, no LDS ----------
// S^T = mfma_16x16x32_f16(Kfrag, Qfrag): lane holds S^T[key=quad*4+r][q=lane&15].
// That C-layout IS the A-layout for PV mfma_16x16x16f16 (m=q=lane&15, k=key=quad*4+j).
// O (16q x 32d) = two C-frags; online softmax via 2 shfl_xor reductions.
// pacc[((b*H+h)*NS+split)*Sn + q][32] fp32, pml[...][2] = (m,l)
__global__ __launch_bounds__(256) void attn_kernel(
    const _Float16* __restrict__ Qh, const _Float16* __restrict__ Kh,
    const _Float16* __restrict__ Vt, const int* __restrict__ len,
    float* __restrict__ pacc, float* __restrict__ pml) {
  const int split = blockIdx.x & (NS - 1);
  const int qg = blockIdx.x >> 2;      // log2(NS)
  const int h = blockIdx.y, b = blockIdx.z;
  const int L = len[b];
  const int lane = threadIdx.x & 63;
  const int wv = threadIdx.x >> 6;     // 4 waves/block, independent q-tiles
  const int q0 = (qg * 4 + wv) * 16;
  if (q0 >= L) return;                 // wave-uniform exit
  const int ks = split * CHUNK;
  if (ks >= L) return;
  const int ke = min(L, ks + CHUNK);

  const int quad = lane >> 4;
  const int l15 = lane & 15;
  const size_t bh = (size_t)(b * Hn + h) * Sn;
  const _Float16* Vt0 = &Vt[(size_t)(b * Hn + h) * Dn * Sn];

  // Q-frag (B-operand): B[k=dim=quad*8+j][n=q=l15]
  const half8_t qf = *(const half8_t*)&Qh[(bh + q0 + l15) * Dn + quad * 8];

  float4_t o0 = {0.f, 0.f, 0.f, 0.f};
  float4_t o1 = {0.f, 0.f, 0.f, 0.f};
  float m = -1.0e30f, l = 0.f;

  for (int k0 = ks; k0 < ke; k0 += 16) {
    // K-frag (A-operand): A[m=key=l15][k=dim=quad*8+j]
    const half8_t kf = *(const half8_t*)&Kh[(bh + k0 + l15) * Dn + quad * 8];
    float4_t st = {0.f, 0.f, 0.f, 0.f};
    st = __builtin_amdgcn_mfma_f32_16x16x32_f16(kf, qf, st, 0, 0, 0);

    const int keybase = k0 + quad * 4;
    float s0 = (keybase + 0 < ke) ? st[0] : -3.0e38f;
    float s1 = (keybase + 1 < ke) ? st[1] : -3.0e38f;
    float s2 = (keybase + 2 < ke) ? st[2] : -3.0e38f;
    float s3 = (keybase + 3 < ke) ? st[3] : -3.0e38f;

    // per-query (column) tile max: reduce 4 regs, then across quads (lane bits 4,5)
    float t = fmaxf(fmaxf(s0, s1), fmaxf(s2, s3));
    t = fmaxf(t, __shfl_xor(t, 16));
    t = fmaxf(t, __shfl_xor(t, 32));
    const float nm = fmaxf(m, t);
    const float sc = __expf(m - nm);
    const float p0 = __expf(s0 - nm);
    const float p1 = __expf(s1 - nm);
    const float p2 = __expf(s2 - nm);
    const float p3 = __expf(s3 - nm);
    float ps = ((p0 + p1) + (p2 + p3));
    ps += __shfl_xor(ps, 16);
    ps += __shfl_xor(ps, 32);
    l = l * sc + ps;
    m = nm;

    // rescale O rows: row query = quad*4+r, sc replicated across quads at lane q
    float4_t scr;
#pragma unroll
    for (int r = 0; r < 4; ++r) scr[r] = __shfl(sc, quad * 4 + r);
#pragma unroll
    for (int r = 0; r < 4; ++r) { o0[r] *= scr[r]; o1[r] *= scr[r]; }

    // P-frag (A-operand of 16x16x16): A[m=q=l15][k=key=quad*4+j] == lane's p regs
    half4_t pf;
    pf[0] = (_Float16)p0; pf[1] = (_Float16)p1;
    pf[2] = (_Float16)p2; pf[3] = (_Float16)p3;
    // V-frags (B-operand): B[k=key=quad*4+j][n=d=l15(+16)] from Vt[d][s]
    const half4_t v0 = *(const half4_t*)&Vt0[(size_t)l15 * Sn + keybase];
    const half4_t v1 = *(const half4_t*)&Vt0[(size_t)(l15 + 16) * Sn + keybase];
    o0 = __builtin_amdgcn_mfma_f32_16x16x16f16(pf, v0, o0, 0, 0, 0);
    o1 = __builtin_amdgcn_mfma_f32_16x16x16f16(pf, v1, o1, 0, 0, 0);
  }

  // store partials: O C-layout row=q'=quad*4+r, col=d=l15(+16)
  const size_t idx0 = ((size_t)(b * Hn + h) * NS + split) * Sn + q0;
#pragma unroll
  for (int r = 0; r < 4; ++r) {
    const int qr = quad * 4 + r;
    float* pp = &pacc[(idx0 + qr) * 32];
    pp[l15] = o0[r];
    pp[l15 + 16] = o1[r];
  }
  if (quad == 0)  // lanes 0..15 hold (m,l) for q = l15
    *(float2*)&pml[(idx0 + l15) * 2] = make_float2(m, l);
}

// ---------- merge key-splits, write scrambled P: P[b].flat[h*L*D + q*D + d] ----------
__global__ __launch_bounds__(256) void combine_kernel(const float* __restrict__ pacc,
                                                      const float* __restrict__ pml,
                                                      const int* __restrict__ len,
                                                      float* __restrict__ P) {
  const int h = blockIdx.y, b = blockIdx.z;
  const int L = len[b];
  const int q = blockIdx.x * 256 + threadIdx.x;
  if (q >= L) return;
  const size_t base = (size_t)(b * Hn + h) * NS * Sn;

  float M = -INFINITY;
  int ns = 0;
  float ms[NS], ls[NS];
#pragma unroll
  for (int sp = 0; sp < NS; ++sp) {
    if (sp * CHUNK < L) {
      float2 ml = *(const float2*)&pml[(base + (size_t)sp * Sn + q) * 2];
      ms[sp] = ml.x; ls[sp] = ml.y;
      M = fmaxf(M, ml.x);
      ns = sp + 1;
    }
  }
  float T = 0.f;
  float o[32];
#pragma unroll
  for (int d = 0; d < 32; ++d) o[d] = 0.f;
  for (int sp = 0; sp < ns; ++sp) {
    float w = __expf(ms[sp] - M);
    T += ls[sp] * w;
    const float4* pp = (const float4*)&pacc[(base + (size_t)sp * Sn + q) * 32];
#pragma unroll
    for (int i = 0; i < 8; ++i) {
      float4 v = pp[i];
      o[i * 4 + 0] = fmaf(w, v.x, o[i * 4 + 0]);
      o[i * 4 + 1] = fmaf(w, v.y, o[i * 4 + 1]);
      o[i * 4 + 2] = fmaf(w, v.z, o[i * 4 + 2]);
      o[i * 4 + 3] = fmaf(w, v.w, o[i * 4 + 3]);
    }
  }
  const float inv = 1.0f / T;
  float* dst = &P[(size_t)b * Sn * En + (size_t)h * L * Dn + (size_t)q * Dn];
#pragma unroll
  for (int i = 0; i < 8; ++i) {
    float4 v = make_float4(o[i * 4] * inv, o[i * 4 + 1] * inv,
                           o[i * 4 + 2] * inv, o[i * 4 + 3] * inv);
    *(float4*)&dst[i * 4] = v;
  }
}

// ---------- zero P tail [L*E, S*E) per batch ----------
__global__ __launch_bounds__(256) void ztail_kernel(const int* __restrict__ len,
                                                    float* __restrict__ P) {
  const int b = blockIdx.y;
  const int L = len[b];
  const int idx = (blockIdx.x * 256 + threadIdx.x) * 4;
  if (idx >= L * En)
    *(float4*)&P[(size_t)b * Sn * En + idx] = make_float4(0.f, 0.f, 0.f, 0.f);
}

extern "C" void kernel_launch(void* const* d_in, const int* in_sizes, int n_in,
                              void* d_out, int out_size, void* d_ws, size_t ws_size,
                              hipStream_t stream) {
  (void)in_sizes; (void)n_in; (void)out_size; (void)ws_size;
  const float* x  = (const float*)d_in[0];  // fp32 (B,S,E)
  const int* mask = (const int*)d_in[1];    // int32 (B,S)
  const float* Wq = (const float*)d_in[2];  // fp32 (E,E)
  const float* Wk = (const float*)d_in[3];
  const float* Wv = (const float*)d_in[4];
  const float* Wo = (const float*)d_in[5];
  float* out = (float*)d_out;               // fp32 (B,S,E)

  // workspace: lengths | Qh,Kh (f16 BHSD) | Vt (f16, transposed) | P | pacc | pml (~56 MB)
  float* wsf = (float*)d_ws;
  int* lengths = (int*)d_ws;
  const size_t BHSD = (size_t)Bn * Hn * Sn * Dn;  // 2,097,152
  _Float16* Qh = (_Float16*)(wsf + 64);
  _Float16* Kh = Qh + BHSD;
  _Float16* Vt = Kh + BHSD;
  float* Pw = (float*)(Vt + BHSD);
  float* pacc = Pw + (size_t)Bn * Sn * En;
  float* pml = pacc + (size_t)Bn * Hn * NS * Sn * 32;

  len_kernel<<<dim3(Bn), 256, 0, stream>>>(mask, lengths);
  gemm_k<128, 128, 8, 8, 0><<<dim3(6, 64), 256, 0, stream>>>(
      x, Wq, Wk, Wv, Qh, Kh, Vt, nullptr);
  attn_kernel<<<dim3((Sn / 64) * NS, Hn, Bn), 256, 0, stream>>>(
      Qh, Kh, Vt, lengths, pacc, pml);
  combine_kernel<<<dim3(Sn / 256, Hn, Bn), 256, 0, stream>>>(
      pacc, pml, lengths, Pw);
  ztail_kernel<<<dim3(Sn * En / 1024, Bn), 256, 0, stream>>>(lengths, Pw);
  gemm_k<64, 128, 4, 8, 1><<<dim3(2, 128), 256, 0, stream>>>(
      Pw, Wo, Wo, Wo, nullptr, nullptr, nullptr, out);
}

// Round 12
// 237.737 us; speedup vs baseline: 2.6738x; 1.1886x over previous
//
#include <hip/hip_runtime.h>
#include <cmath>

// Problem constants
#define Bn 4
#define Sn 2048
#define En 256
#define Hn 8
#define Dn 32
#define KD 256          // inner GEMM dim (= En)
#define NS 4            // key splits for attention
#define CHUNK 512       // keys per split

static constexpr float SCALE_F = 0.17677669529663687f;  // 32^-0.5

typedef _Float16 half4_t __attribute__((ext_vector_type(4)));
typedef _Float16 half8_t __attribute__((ext_vector_type(8)));
typedef float float4_t __attribute__((ext_vector_type(4)));

// ---------- lengths[b] = sum(mask[b,:]) ----------
__global__ __launch_bounds__(256) void len_kernel(const int* __restrict__ mask,
                                                  int* __restrict__ len) {
  int b = blockIdx.x, t = threadIdx.x;
  int s = 0;
  for (int i = t; i < Sn; i += 256) s += mask[b * Sn + i];
#pragma unroll
  for (int off = 32; off > 0; off >>= 1) s += __shfl_down(s, off, 64);
  __shared__ int red[4];
  if ((t & 63) == 0) red[t >> 6] = s;
  __syncthreads();
  if (t == 0) len[b] = red[0] + red[1] + red[2] + red[3];
}

// ---------- tiled GEMM: C[M,N] = A[M,256] @ W[N,256]^T  (fp32 in) ----------
// EPI==0: writes f16 Qh (scaled), Kh row-major (B,H,S,D); Vt transposed (B,H,D,S)
// EPI==1: A = P (fp32 scrambled), W0 = Wo; fp32 d_out
template <int BM, int BN, int TM, int TN, int EPI>
__global__ __launch_bounds__(256) void gemm_k(
    const float* __restrict__ Ap,
    const float* __restrict__ W0,
    const float* __restrict__ W1,
    const float* __restrict__ W2,
    _Float16* __restrict__ Qh, _Float16* __restrict__ Kh, _Float16* __restrict__ Vt,
    float* __restrict__ Oout) {
  constexpr int BK = 32;
  __shared__ __align__(16) float As[BK][BM + 4];
  __shared__ __align__(16) float Bs[BK][BN + 4];
  const int tid = threadIdx.x;
  const int j0 = blockIdx.x * BN;
  const int i0 = blockIdx.y * BM;

  const float* Wp;
  int jc0;
  if constexpr (EPI == 0) {
    const int mat = j0 >> 8;
    Wp = (mat == 0) ? W0 : ((mat == 1) ? W1 : W2);
    jc0 = j0 & 255;
  } else {
    Wp = W0;
    jc0 = j0;
  }

  float acc[TM][TN];
#pragma unroll
  for (int ii = 0; ii < TM; ++ii)
#pragma unroll
    for (int jj = 0; jj < TN; ++jj) acc[ii][jj] = 0.f;

  for (int k0 = 0; k0 < KD; k0 += BK) {
#pragma unroll
    for (int it = 0; it < (BM * BK / 4) / 256; ++it) {
      int c4 = tid + it * 256;
      int row = c4 >> 3, kk4 = (c4 & 7) * 4;
      float4 v = *(const float4*)&Ap[(size_t)(i0 + row) * KD + k0 + kk4];
      As[kk4 + 0][row] = v.x; As[kk4 + 1][row] = v.y;
      As[kk4 + 2][row] = v.z; As[kk4 + 3][row] = v.w;
    }
#pragma unroll
    for (int it = 0; it < (BN * BK / 4) / 256; ++it) {
      int c4 = tid + it * 256;
      int row = c4 >> 3, kk4 = (c4 & 7) * 4;
      float4 v = *(const float4*)&Wp[(size_t)(jc0 + row) * KD + k0 + kk4];
      Bs[kk4 + 0][row] = v.x; Bs[kk4 + 1][row] = v.y;
      Bs[kk4 + 2][row] = v.z; Bs[kk4 + 3][row] = v.w;
    }
    __syncthreads();
    {
      const int tx = tid & 15, ty = tid >> 4;
#pragma unroll
      for (int kk = 0; kk < BK; ++kk) {
        float a[TM], bb[TN];
#pragma unroll
        for (int ii = 0; ii < TM; ++ii) a[ii] = As[kk][ty * TM + ii];
#pragma unroll
        for (int jj = 0; jj < TN; ++jj) bb[jj] = Bs[kk][tx * TN + jj];
#pragma unroll
        for (int ii = 0; ii < TM; ++ii)
#pragma unroll
          for (int jj = 0; jj < TN; ++jj)
            acc[ii][jj] = fmaf(a[ii], bb[jj], acc[ii][jj]);
      }
    }
    __syncthreads();
  }

  const int tx = tid & 15, ty = tid >> 4;
  if constexpr (EPI == 0) {
    const int mat = j0 >> 8;
    const float scale = (mat == 0) ? SCALE_F : 1.0f;  // fold softmax scale into Q
#pragma unroll
    for (int ii = 0; ii < TM; ++ii) {
      int i = i0 + ty * TM + ii;
      int bb_ = i >> 11, s = i & (Sn - 1);
#pragma unroll
      for (int jj = 0; jj < TN; jj += 4) {
        int c = jc0 + tx * TN + jj;   // 4-aligned -> same head
        int h = c >> 5, d = c & 31;
        if (mat == 2) {               // V transposed: Vt[(bh*32+d)][s]
#pragma unroll
          for (int t2 = 0; t2 < 4; ++t2)
            Vt[((size_t)(bb_ * Hn + h) * Dn + d + t2) * Sn + s] =
                (_Float16)acc[ii][jj + t2];
        } else {
          _Float16* dstH = (mat == 0) ? Qh : Kh;
          half4_t hv;
          hv[0] = (_Float16)(acc[ii][jj + 0] * scale);
          hv[1] = (_Float16)(acc[ii][jj + 1] * scale);
          hv[2] = (_Float16)(acc[ii][jj + 2] * scale);
          hv[3] = (_Float16)(acc[ii][jj + 3] * scale);
          *(half4_t*)&dstH[((size_t)(bb_ * Hn + h) * Sn + s) * Dn + d] = hv;
        }
      }
    }
  } else {
#pragma unroll
    for (int ii = 0; ii < TM; ++ii) {
      int i = i0 + ty * TM + ii;
#pragma unroll
      for (int jj = 0; jj < TN; jj += 4) {
        int j = j0 + tx * TN + jj;
        float4 v = make_float4(acc[ii][jj], acc[ii][jj + 1],
                               acc[ii][jj + 2], acc[ii][jj + 3]);
        *(float4*)&Oout[(size_t)i * En + j] = v;
      }
    }
  }
}

// ---------- MFMA flash attention: wave = 2 q-tiles (32 q) x 32-key steps ----------
// S^T = mfma_16x16x32_f16(Kfrag, Qfrag): C-layout col=q=lane&15, row=key=quad*4+reg.
// That IS the A-layout for PV mfma_16x16x16f16. K/V frags shared by both q-tiles;
// two independent softmax chains overlap; one rescale round per 32 keys per tile.
// pacc[((b*H+h)*NS+split)*Sn + q][32] fp32, pml[...][2] = (m,l)
__global__ __launch_bounds__(256) void attn_kernel(
    const _Float16* __restrict__ Qh, const _Float16* __restrict__ Kh,
    const _Float16* __restrict__ Vt, const int* __restrict__ len,
    float* __restrict__ pacc, float* __restrict__ pml) {
  const int split = blockIdx.x & (NS - 1);
  const int qg = blockIdx.x >> 2;      // log2(NS)
  const int h = blockIdx.y, b = blockIdx.z;
  const int L = len[b];
  const int lane = threadIdx.x & 63;
  const int wv = threadIdx.x >> 6;     // 4 waves/block, independent 32-query tiles
  const int q0 = (qg * 4 + wv) * 32;
  if (q0 >= L) return;                 // wave-uniform exit (no LDS/barriers in kernel)
  const int ks = split * CHUNK;
  if (ks >= L) return;
  const int ke = min(L, ks + CHUNK);

  const int quad = lane >> 4;
  const int l15 = lane & 15;
  const size_t bh = (size_t)(b * Hn + h) * Sn;
  const _Float16* Vt0 = &Vt[(size_t)(b * Hn + h) * Dn * Sn];

  // Q-frags (B-operand): B[k=dim=quad*8+j][n=q=l15]; tiles at q0 and q0+16
  const half8_t qfA = *(const half8_t*)&Qh[(bh + q0 + l15) * Dn + quad * 8];
  const half8_t qfB = *(const half8_t*)&Qh[(bh + q0 + 16 + l15) * Dn + quad * 8];

  float4_t oA0 = {0.f, 0.f, 0.f, 0.f}, oA1 = {0.f, 0.f, 0.f, 0.f};
  float4_t oB0 = {0.f, 0.f, 0.f, 0.f}, oB1 = {0.f, 0.f, 0.f, 0.f};
  float mA = -1.0e30f, lA = 0.f;
  float mB = -1.0e30f, lB = 0.f;

  for (int k0 = ks; k0 < ke; k0 += 32) {
    // K-frags (A-operand): A[m=key=l15][k=dim=quad*8+j], steps a=k0, b=k0+16
    const half8_t kfa = *(const half8_t*)&Kh[(bh + k0 + l15) * Dn + quad * 8];
    const half8_t kfb = *(const half8_t*)&Kh[(bh + k0 + 16 + l15) * Dn + quad * 8];
    float4_t stAa = {0.f, 0.f, 0.f, 0.f}, stAb = {0.f, 0.f, 0.f, 0.f};
    float4_t stBa = {0.f, 0.f, 0.f, 0.f}, stBb = {0.f, 0.f, 0.f, 0.f};
    stAa = __builtin_amdgcn_mfma_f32_16x16x32_f16(kfa, qfA, stAa, 0, 0, 0);
    stAb = __builtin_amdgcn_mfma_f32_16x16x32_f16(kfb, qfA, stAb, 0, 0, 0);
    stBa = __builtin_amdgcn_mfma_f32_16x16x32_f16(kfa, qfB, stBa, 0, 0, 0);
    stBb = __builtin_amdgcn_mfma_f32_16x16x32_f16(kfb, qfB, stBb, 0, 0, 0);

    const int ka = k0 + quad * 4;        // keys of a-step regs
    const int kb = k0 + 16 + quad * 4;   // keys of b-step regs
#pragma unroll
    for (int r = 0; r < 4; ++r) {
      if (ka + r >= ke) { stAa[r] = -3.0e38f; stBa[r] = -3.0e38f; }
      if (kb + r >= ke) { stAb[r] = -3.0e38f; stBb[r] = -3.0e38f; }
    }

    // ---- two independent softmax chains (A and B overlap in the pipeline) ----
    float tA = fmaxf(fmaxf(fmaxf(stAa[0], stAa[1]), fmaxf(stAa[2], stAa[3])),
                     fmaxf(fmaxf(stAb[0], stAb[1]), fmaxf(stAb[2], stAb[3])));
    float tB = fmaxf(fmaxf(fmaxf(stBa[0], stBa[1]), fmaxf(stBa[2], stBa[3])),
                     fmaxf(fmaxf(stBb[0], stBb[1]), fmaxf(stBb[2], stBb[3])));
    tA = fmaxf(tA, __shfl_xor(tA, 16)); tB = fmaxf(tB, __shfl_xor(tB, 16));
    tA = fmaxf(tA, __shfl_xor(tA, 32)); tB = fmaxf(tB, __shfl_xor(tB, 32));
    const float nmA = fmaxf(mA, tA), nmB = fmaxf(mB, tB);
    const float scA = __expf(mA - nmA), scB = __expf(mB - nmB);
    float pAa[4], pAb[4], pBa[4], pBb[4];
#pragma unroll
    for (int r = 0; r < 4; ++r) {
      pAa[r] = __expf(stAa[r] - nmA); pAb[r] = __expf(stAb[r] - nmA);
      pBa[r] = __expf(stBa[r] - nmB); pBb[r] = __expf(stBb[r] - nmB);
    }
    float psA = ((pAa[0] + pAa[1]) + (pAa[2] + pAa[3])) +
                ((pAb[0] + pAb[1]) + (pAb[2] + pAb[3]));
    float psB = ((pBa[0] + pBa[1]) + (pBa[2] + pBa[3])) +
                ((pBb[0] + pBb[1]) + (pBb[2] + pBb[3]));
    psA += __shfl_xor(psA, 16); psB += __shfl_xor(psB, 16);
    psA += __shfl_xor(psA, 32); psB += __shfl_xor(psB, 32);
    lA = lA * scA + psA; lB = lB * scB + psB;
    mA = nmA; mB = nmB;

    // rescale O rows (row query = quad*4+r): sc broadcast from lane holding that q
#pragma unroll
    for (int r = 0; r < 4; ++r) {
      const float sA = __shfl(scA, quad * 4 + r);
      const float sB = __shfl(scB, quad * 4 + r);
      oA0[r] *= sA; oA1[r] *= sA;
      oB0[r] *= sB; oB1[r] *= sB;
    }

    // P-frags (A-operand 16x16x16): A[m=q=l15][k=key=quad*4+j]
    half4_t pfAa, pfAb, pfBa, pfBb;
#pragma unroll
    for (int r = 0; r < 4; ++r) {
      pfAa[r] = (_Float16)pAa[r]; pfAb[r] = (_Float16)pAb[r];
      pfBa[r] = (_Float16)pBa[r]; pfBb[r] = (_Float16)pBb[r];
    }
    // V-frags (B-operand): B[k=key][n=d=l15(+16)] from Vt[d][s]; shared by A,B tiles
    const half4_t v0a = *(const half4_t*)&Vt0[(size_t)l15 * Sn + ka];
    const half4_t v1a = *(const half4_t*)&Vt0[(size_t)(l15 + 16) * Sn + ka];
    const half4_t v0b = *(const half4_t*)&Vt0[(size_t)l15 * Sn + kb];
    const half4_t v1b = *(const half4_t*)&Vt0[(size_t)(l15 + 16) * Sn + kb];
    oA0 = __builtin_amdgcn_mfma_f32_16x16x16f16(pfAa, v0a, oA0, 0, 0, 0);
    oA1 = __builtin_amdgcn_mfma_f32_16x16x16f16(pfAa, v1a, oA1, 0, 0, 0);
    oA0 = __builtin_amdgcn_mfma_f32_16x16x16f16(pfAb, v0b, oA0, 0, 0, 0);
    oA1 = __builtin_amdgcn_mfma_f32_16x16x16f16(pfAb, v1b, oA1, 0, 0, 0);
    oB0 = __builtin_amdgcn_mfma_f32_16x16x16f16(pfBa, v0a, oB0, 0, 0, 0);
    oB1 = __builtin_amdgcn_mfma_f32_16x16x16f16(pfBa, v1a, oB1, 0, 0, 0);
    oB0 = __builtin_amdgcn_mfma_f32_16x16x16f16(pfBb, v0b, oB0, 0, 0, 0);
    oB1 = __builtin_amdgcn_mfma_f32_16x16x16f16(pfBb, v1b, oB1, 0, 0, 0);
  }

  // store partials: O C-layout row=q'=quad*4+r, col=d=l15(+16)
  const size_t idx0 = ((size_t)(b * Hn + h) * NS + split) * Sn + q0;
#pragma unroll
  for (int r = 0; r < 4; ++r) {
    const int qr = quad * 4 + r;
    float* ppA = &pacc[(idx0 + qr) * 32];
    ppA[l15] = oA0[r];
    ppA[l15 + 16] = oA1[r];
    float* ppB = &pacc[(idx0 + 16 + qr) * 32];
    ppB[l15] = oB0[r];
    ppB[l15 + 16] = oB1[r];
  }
  if (quad == 0) {  // lanes 0..15 hold (m,l) for q = l15 (tile A) and q0+16+l15 (tile B)
    *(float2*)&pml[(idx0 + l15) * 2] = make_float2(mA, lA);
    *(float2*)&pml[(idx0 + 16 + l15) * 2] = make_float2(mB, lB);
  }
}

// ---------- merge key-splits, write scrambled P: P[b].flat[h*L*D + q*D + d] ----------
__global__ __launch_bounds__(256) void combine_kernel(const float* __restrict__ pacc,
                                                      const float* __restrict__ pml,
                                                      const int* __restrict__ len,
                                                      float* __restrict__ P) {
  const int h = blockIdx.y, b = blockIdx.z;
  const int L = len[b];
  const int q = blockIdx.x * 256 + threadIdx.x;
  if (q >= L) return;
  const size_t base = (size_t)(b * Hn + h) * NS * Sn;

  float M = -INFINITY;
  int ns = 0;
  float ms[NS], ls[NS];
#pragma unroll
  for (int sp = 0; sp < NS; ++sp) {
    if (sp * CHUNK < L) {
      float2 ml = *(const float2*)&pml[(base + (size_t)sp * Sn + q) * 2];
      ms[sp] = ml.x; ls[sp] = ml.y;
      M = fmaxf(M, ml.x);
      ns = sp + 1;
    }
  }
  float T = 0.f;
  float o[32];
#pragma unroll
  for (int d = 0; d < 32; ++d) o[d] = 0.f;
  for (int sp = 0; sp < ns; ++sp) {
    float w = __expf(ms[sp] - M);
    T += ls[sp] * w;
    const float4* pp = (const float4*)&pacc[(base + (size_t)sp * Sn + q) * 32];
#pragma unroll
    for (int i = 0; i < 8; ++i) {
      float4 v = pp[i];
      o[i * 4 + 0] = fmaf(w, v.x, o[i * 4 + 0]);
      o[i * 4 + 1] = fmaf(w, v.y, o[i * 4 + 1]);
      o[i * 4 + 2] = fmaf(w, v.z, o[i * 4 + 2]);
      o[i * 4 + 3] = fmaf(w, v.w, o[i * 4 + 3]);
    }
  }
  const float inv = 1.0f / T;
  float* dst = &P[(size_t)b * Sn * En + (size_t)h * L * Dn + (size_t)q * Dn];
#pragma unroll
  for (int i = 0; i < 8; ++i) {
    float4 v = make_float4(o[i * 4] * inv, o[i * 4 + 1] * inv,
                           o[i * 4 + 2] * inv, o[i * 4 + 3] * inv);
    *(float4*)&dst[i * 4] = v;
  }
}

// ---------- zero P tail [L*E, S*E) per batch ----------
__global__ __launch_bounds__(256) void ztail_kernel(const int* __restrict__ len,
                                                    float* __restrict__ P) {
  const int b = blockIdx.y;
  const int L = len[b];
  const int idx = (blockIdx.x * 256 + threadIdx.x) * 4;
  if (idx >= L * En)
    *(float4*)&P[(size_t)b * Sn * En + idx] = make_float4(0.f, 0.f, 0.f, 0.f);
}

extern "C" void kernel_launch(void* const* d_in, const int* in_sizes, int n_in,
                              void* d_out, int out_size, void* d_ws, size_t ws_size,
                              hipStream_t stream) {
  (void)in_sizes; (void)n_in; (void)out_size; (void)ws_size;
  const float* x  = (const float*)d_in[0];  // fp32 (B,S,E)
  const int* mask = (const int*)d_in[1];    // int32 (B,S)
  const float* Wq = (const float*)d_in[2];  // fp32 (E,E)
  const float* Wk = (const float*)d_in[3];
  const float* Wv = (const float*)d_in[4];
  const float* Wo = (const float*)d_in[5];
  float* out = (float*)d_out;               // fp32 (B,S,E)

  // workspace: lengths | Qh,Kh (f16 BHSD) | Vt (f16, transposed) | P | pacc | pml (~56 MB)
  float* wsf = (float*)d_ws;
  int* lengths = (int*)d_ws;
  const size_t BHSD = (size_t)Bn * Hn * Sn * Dn;  // 2,097,152
  _Float16* Qh = (_Float16*)(wsf + 64);
  _Float16* Kh = Qh + BHSD;
  _Float16* Vt = Kh + BHSD;
  float* Pw = (float*)(Vt + BHSD);
  float* pacc = Pw + (size_t)Bn * Sn * En;
  float* pml = pacc + (size_t)Bn * Hn * NS * Sn * 32;

  len_kernel<<<dim3(Bn), 256, 0, stream>>>(mask, lengths);
  gemm_k<128, 128, 8, 8, 0><<<dim3(6, 64), 256, 0, stream>>>(
      x, Wq, Wk, Wv, Qh, Kh, Vt, nullptr);
  attn_kernel<<<dim3((Sn / 128) * NS, Hn, Bn), 256, 0, stream>>>(
      Qh, Kh, Vt, lengths, pacc, pml);
  combine_kernel<<<dim3(Sn / 256, Hn, Bn), 256, 0, stream>>>(
      pacc, pml, lengths, Pw);
  ztail_kernel<<<dim3(Sn * En / 1024, Bn), 256, 0, stream>>>(lengths, Pw);
  gemm_k<64, 128, 4, 8, 1><<<dim3(2, 128), 256, 0, stream>>>(
      Pw, Wo, Wo, Wo, nullptr, nullptr, nullptr, out);
}

// Round 13
// 188.145 us; speedup vs baseline: 3.3786x; 1.2636x over previous
//
#include <hip/hip_runtime.h>
#include <cmath>

// Problem constants
#define Bn 4
#define Sn 2048
#define En 256
#define Hn 8
#define Dn 32
#define KD 256          // inner GEMM dim (= En)
#define NS 4            // key splits for attention
#define CHUNK 512       // keys per split

static constexpr float SCALE_F = 0.17677669529663687f;  // 32^-0.5

typedef _Float16 half4_t __attribute__((ext_vector_type(4)));
typedef _Float16 half8_t __attribute__((ext_vector_type(8)));
typedef float float4_t __attribute__((ext_vector_type(4)));

// ---------- lengths[b] = sum(mask[b,:]) ----------
__global__ __launch_bounds__(256) void len_kernel(const int* __restrict__ mask,
                                                  int* __restrict__ len) {
  int b = blockIdx.x, t = threadIdx.x;
  int s = 0;
  for (int i = t; i < Sn; i += 256) s += mask[b * Sn + i];
#pragma unroll
  for (int off = 32; off > 0; off >>= 1) s += __shfl_down(s, off, 64);
  __shared__ int red[4];
  if ((t & 63) == 0) red[t >> 6] = s;
  __syncthreads();
  if (t == 0) len[b] = red[0] + red[1] + red[2] + red[3];
}

// ---------- fp32 -> f16 convert: x (2M) then Wq|Wk|Wv|Wo (64K each) ----------
__global__ __launch_bounds__(256) void cvt_kernel(
    const float* __restrict__ x, const float* __restrict__ Wq,
    const float* __restrict__ Wk, const float* __restrict__ Wv,
    const float* __restrict__ Wo, _Float16* __restrict__ xh,
    _Float16* __restrict__ Wh) {
  const size_t base = ((size_t)blockIdx.x * 256 + threadIdx.x) * 8;
  const float* src; _Float16* dst; size_t off;
  if (base < 2097152) { src = x; dst = xh; off = base; }
  else {
    size_t wi = base - 2097152;        // 0 .. 262143
    int w = (int)(wi >> 16);           // 0..3
    off = wi & 65535;
    src = (w == 0) ? Wq : (w == 1) ? Wk : (w == 2) ? Wv : Wo;
    dst = Wh + (size_t)w * 65536;
  }
  float4 a = *(const float4*)&src[off];
  float4 b2 = *(const float4*)&src[off + 4];
  half8_t h;
  h[0] = (_Float16)a.x;  h[1] = (_Float16)a.y;
  h[2] = (_Float16)a.z;  h[3] = (_Float16)a.w;
  h[4] = (_Float16)b2.x; h[5] = (_Float16)b2.y;
  h[6] = (_Float16)b2.z; h[7] = (_Float16)b2.w;
  *(half8_t*)&dst[off] = h;
}

// ---------- QKV MFMA GEMM: [8192,256]f16 @ [768,256]^T f16 ----------
// Wave = 64m x 64n (16 C-frags), block = 4 waves = 256m x 64n, grid (12, 32).
// A-frag: xh[(m+l15)*256 + k0+quad*8]; B-frag: Wh[(n+l15)*256 + k0+quad*8].
// C layout: col=n=lane&15, row=m=quad*4+reg (validated by attention kernel).
// Epilogue: n-block 0-3 -> Qh (*SCALE), 4-7 -> Kh, 8-11 -> Vt (transposed).
__global__ __launch_bounds__(256) void qkv_gemm(
    const _Float16* __restrict__ xh, const _Float16* __restrict__ Wh,
    _Float16* __restrict__ Qh, _Float16* __restrict__ Kh,
    _Float16* __restrict__ Vt) {
  const int lane = threadIdx.x & 63;
  const int wv = threadIdx.x >> 6;
  const int quad = lane >> 4, l15 = lane & 15;
  const int n0 = blockIdx.x * 64;          // matrix = n0>>8, uniform per block
  const int mw = blockIdx.y * 256 + wv * 64;

  float4_t C[4][4];
#pragma unroll
  for (int i = 0; i < 4; ++i)
#pragma unroll
    for (int j = 0; j < 4; ++j) C[i][j] = (float4_t){0.f, 0.f, 0.f, 0.f};

  for (int k0 = 0; k0 < KD; k0 += 32) {
    half8_t A[4], Bf[4];
#pragma unroll
    for (int i = 0; i < 4; ++i)
      A[i] = *(const half8_t*)&xh[(size_t)(mw + 16 * i + l15) * KD + k0 + quad * 8];
#pragma unroll
    for (int j = 0; j < 4; ++j)
      Bf[j] = *(const half8_t*)&Wh[(size_t)(n0 + 16 * j + l15) * KD + k0 + quad * 8];
#pragma unroll
    for (int i = 0; i < 4; ++i)
#pragma unroll
      for (int j = 0; j < 4; ++j)
        C[i][j] = __builtin_amdgcn_mfma_f32_16x16x32_f16(A[i], Bf[j], C[i][j], 0, 0, 0);
  }

  const int mat = n0 >> 8;
  if (mat < 2) {
    _Float16* dstH = mat ? Kh : Qh;
    const float scale = mat ? 1.0f : SCALE_F;   // fold softmax scale into Q
#pragma unroll
    for (int i = 0; i < 4; ++i)
#pragma unroll
      for (int j = 0; j < 4; ++j) {
        const int c = ((n0 + 16 * j) & 255) + l15;
        const int h = c >> 5, d = c & 31;
#pragma unroll
        for (int r = 0; r < 4; ++r) {
          const int m = mw + 16 * i + quad * 4 + r;
          const int b = m >> 11, s = m & (Sn - 1);
          dstH[((size_t)(b * Hn + h) * Sn + s) * Dn + d] =
              (_Float16)(C[i][j][r] * scale);
        }
      }
  } else {
#pragma unroll
    for (int i = 0; i < 4; ++i)
#pragma unroll
      for (int j = 0; j < 4; ++j) {
        const int c = ((n0 + 16 * j) & 255) + l15;
        const int h = c >> 5, d = c & 31;
        const int m = mw + 16 * i + quad * 4;   // 4 consecutive s -> one half4
        const int b = m >> 11, s = m & (Sn - 1);
        half4_t hv;
#pragma unroll
        for (int r = 0; r < 4; ++r) hv[r] = (_Float16)C[i][j][r];
        *(half4_t*)&Vt[((size_t)(b * Hn + h) * Dn + d) * Sn + s] = hv;
      }
  }
}

// ---------- output MFMA GEMM: [8192,256]f16 (Ph) @ Wo^T f16 -> fp32 d_out ----------
__global__ __launch_bounds__(256) void out_gemm(
    const _Float16* __restrict__ Ph, const _Float16* __restrict__ Woh,
    float* __restrict__ out) {
  const int lane = threadIdx.x & 63;
  const int wv = threadIdx.x >> 6;
  const int quad = lane >> 4, l15 = lane & 15;
  const int n0 = blockIdx.x * 64;
  const int mw = blockIdx.y * 256 + wv * 64;

  float4_t C[4][4];
#pragma unroll
  for (int i = 0; i < 4; ++i)
#pragma unroll
    for (int j = 0; j < 4; ++j) C[i][j] = (float4_t){0.f, 0.f, 0.f, 0.f};

  for (int k0 = 0; k0 < KD; k0 += 32) {
    half8_t A[4], Bf[4];
#pragma unroll
    for (int i = 0; i < 4; ++i)
      A[i] = *(const half8_t*)&Ph[(size_t)(mw + 16 * i + l15) * KD + k0 + quad * 8];
#pragma unroll
    for (int j = 0; j < 4; ++j)
      Bf[j] = *(const half8_t*)&Woh[(size_t)(n0 + 16 * j + l15) * KD + k0 + quad * 8];
#pragma unroll
    for (int i = 0; i < 4; ++i)
#pragma unroll
      for (int j = 0; j < 4; ++j)
        C[i][j] = __builtin_amdgcn_mfma_f32_16x16x32_f16(A[i], Bf[j], C[i][j], 0, 0, 0);
  }

#pragma unroll
  for (int i = 0; i < 4; ++i)
#pragma unroll
    for (int j = 0; j < 4; ++j)
#pragma unroll
      for (int r = 0; r < 4; ++r)
        out[(size_t)(mw + 16 * i + quad * 4 + r) * En + n0 + 16 * j + l15] =
            C[i][j][r];
}

// ---------- MFMA flash attention: wave = 2 q-tiles (32 q) x 32-key steps ----------
// (unchanged from round 12 — 84 us, verified)
__global__ __launch_bounds__(256) void attn_kernel(
    const _Float16* __restrict__ Qh, const _Float16* __restrict__ Kh,
    const _Float16* __restrict__ Vt, const int* __restrict__ len,
    float* __restrict__ pacc, float* __restrict__ pml) {
  const int split = blockIdx.x & (NS - 1);
  const int qg = blockIdx.x >> 2;      // log2(NS)
  const int h = blockIdx.y, b = blockIdx.z;
  const int L = len[b];
  const int lane = threadIdx.x & 63;
  const int wv = threadIdx.x >> 6;     // 4 waves/block, independent 32-query tiles
  const int q0 = (qg * 4 + wv) * 32;
  if (q0 >= L) return;                 // wave-uniform exit (no LDS/barriers)
  const int ks = split * CHUNK;
  if (ks >= L) return;
  const int ke = min(L, ks + CHUNK);

  const int quad = lane >> 4;
  const int l15 = lane & 15;
  const size_t bh = (size_t)(b * Hn + h) * Sn;
  const _Float16* Vt0 = &Vt[(size_t)(b * Hn + h) * Dn * Sn];

  const half8_t qfA = *(const half8_t*)&Qh[(bh + q0 + l15) * Dn + quad * 8];
  const half8_t qfB = *(const half8_t*)&Qh[(bh + q0 + 16 + l15) * Dn + quad * 8];

  float4_t oA0 = {0.f, 0.f, 0.f, 0.f}, oA1 = {0.f, 0.f, 0.f, 0.f};
  float4_t oB0 = {0.f, 0.f, 0.f, 0.f}, oB1 = {0.f, 0.f, 0.f, 0.f};
  float mA = -1.0e30f, lA = 0.f;
  float mB = -1.0e30f, lB = 0.f;

  for (int k0 = ks; k0 < ke; k0 += 32) {
    const half8_t kfa = *(const half8_t*)&Kh[(bh + k0 + l15) * Dn + quad * 8];
    const half8_t kfb = *(const half8_t*)&Kh[(bh + k0 + 16 + l15) * Dn + quad * 8];
    float4_t stAa = {0.f, 0.f, 0.f, 0.f}, stAb = {0.f, 0.f, 0.f, 0.f};
    float4_t stBa = {0.f, 0.f, 0.f, 0.f}, stBb = {0.f, 0.f, 0.f, 0.f};
    stAa = __builtin_amdgcn_mfma_f32_16x16x32_f16(kfa, qfA, stAa, 0, 0, 0);
    stAb = __builtin_amdgcn_mfma_f32_16x16x32_f16(kfb, qfA, stAb, 0, 0, 0);
    stBa = __builtin_amdgcn_mfma_f32_16x16x32_f16(kfa, qfB, stBa, 0, 0, 0);
    stBb = __builtin_amdgcn_mfma_f32_16x16x32_f16(kfb, qfB, stBb, 0, 0, 0);

    const int ka = k0 + quad * 4;
    const int kb = k0 + 16 + quad * 4;
#pragma unroll
    for (int r = 0; r < 4; ++r) {
      if (ka + r >= ke) { stAa[r] = -3.0e38f; stBa[r] = -3.0e38f; }
      if (kb + r >= ke) { stAb[r] = -3.0e38f; stBb[r] = -3.0e38f; }
    }

    float tA = fmaxf(fmaxf(fmaxf(stAa[0], stAa[1]), fmaxf(stAa[2], stAa[3])),
                     fmaxf(fmaxf(stAb[0], stAb[1]), fmaxf(stAb[2], stAb[3])));
    float tB = fmaxf(fmaxf(fmaxf(stBa[0], stBa[1]), fmaxf(stBa[2], stBa[3])),
                     fmaxf(fmaxf(stBb[0], stBb[1]), fmaxf(stBb[2], stBb[3])));
    tA = fmaxf(tA, __shfl_xor(tA, 16)); tB = fmaxf(tB, __shfl_xor(tB, 16));
    tA = fmaxf(tA, __shfl_xor(tA, 32)); tB = fmaxf(tB, __shfl_xor(tB, 32));
    const float nmA = fmaxf(mA, tA), nmB = fmaxf(mB, tB);
    const float scA = __expf(mA - nmA), scB = __expf(mB - nmB);
    float pAa[4], pAb[4], pBa[4], pBb[4];
#pragma unroll
    for (int r = 0; r < 4; ++r) {
      pAa[r] = __expf(stAa[r] - nmA); pAb[r] = __expf(stAb[r] - nmA);
      pBa[r] = __expf(stBa[r] - nmB); pBb[r] = __expf(stBb[r] - nmB);
    }
    float psA = ((pAa[0] + pAa[1]) + (pAa[2] + pAa[3])) +
                ((pAb[0] + pAb[1]) + (pAb[2] + pAb[3]));
    float psB = ((pBa[0] + pBa[1]) + (pBa[2] + pBa[3])) +
                ((pBb[0] + pBb[1]) + (pBb[2] + pBb[3]));
    psA += __shfl_xor(psA, 16); psB += __shfl_xor(psB, 16);
    psA += __shfl_xor(psA, 32); psB += __shfl_xor(psB, 32);
    lA = lA * scA + psA; lB = lB * scB + psB;
    mA = nmA; mB = nmB;

#pragma unroll
    for (int r = 0; r < 4; ++r) {
      const float sA = __shfl(scA, quad * 4 + r);
      const float sB = __shfl(scB, quad * 4 + r);
      oA0[r] *= sA; oA1[r] *= sA;
      oB0[r] *= sB; oB1[r] *= sB;
    }

    half4_t pfAa, pfAb, pfBa, pfBb;
#pragma unroll
    for (int r = 0; r < 4; ++r) {
      pfAa[r] = (_Float16)pAa[r]; pfAb[r] = (_Float16)pAb[r];
      pfBa[r] = (_Float16)pBa[r]; pfBb[r] = (_Float16)pBb[r];
    }
    const half4_t v0a = *(const half4_t*)&Vt0[(size_t)l15 * Sn + ka];
    const half4_t v1a = *(const half4_t*)&Vt0[(size_t)(l15 + 16) * Sn + ka];
    const half4_t v0b = *(const half4_t*)&Vt0[(size_t)l15 * Sn + kb];
    const half4_t v1b = *(const half4_t*)&Vt0[(size_t)(l15 + 16) * Sn + kb];
    oA0 = __builtin_amdgcn_mfma_f32_16x16x16f16(pfAa, v0a, oA0, 0, 0, 0);
    oA1 = __builtin_amdgcn_mfma_f32_16x16x16f16(pfAa, v1a, oA1, 0, 0, 0);
    oA0 = __builtin_amdgcn_mfma_f32_16x16x16f16(pfAb, v0b, oA0, 0, 0, 0);
    oA1 = __builtin_amdgcn_mfma_f32_16x16x16f16(pfAb, v1b, oA1, 0, 0, 0);
    oB0 = __builtin_amdgcn_mfma_f32_16x16x16f16(pfBa, v0a, oB0, 0, 0, 0);
    oB1 = __builtin_amdgcn_mfma_f32_16x16x16f16(pfBa, v1a, oB1, 0, 0, 0);
    oB0 = __builtin_amdgcn_mfma_f32_16x16x16f16(pfBb, v0b, oB0, 0, 0, 0);
    oB1 = __builtin_amdgcn_mfma_f32_16x16x16f16(pfBb, v1b, oB1, 0, 0, 0);
  }

  const size_t idx0 = ((size_t)(b * Hn + h) * NS + split) * Sn + q0;
#pragma unroll
  for (int r = 0; r < 4; ++r) {
    const int qr = quad * 4 + r;
    float* ppA = &pacc[(idx0 + qr) * 32];
    ppA[l15] = oA0[r];
    ppA[l15 + 16] = oA1[r];
    float* ppB = &pacc[(idx0 + 16 + qr) * 32];
    ppB[l15] = oB0[r];
    ppB[l15 + 16] = oB1[r];
  }
  if (quad == 0) {
    *(float2*)&pml[(idx0 + l15) * 2] = make_float2(mA, lA);
    *(float2*)&pml[(idx0 + 16 + l15) * 2] = make_float2(mB, lB);
  }
}

// ---------- merge key-splits, write scrambled Ph (f16) ----------
__global__ __launch_bounds__(256) void combine_kernel(const float* __restrict__ pacc,
                                                      const float* __restrict__ pml,
                                                      const int* __restrict__ len,
                                                      _Float16* __restrict__ Ph) {
  const int h = blockIdx.y, b = blockIdx.z;
  const int L = len[b];
  const int q = blockIdx.x * 256 + threadIdx.x;
  if (q >= L) return;
  const size_t base = (size_t)(b * Hn + h) * NS * Sn;

  float M = -INFINITY;
  int ns = 0;
  float ms[NS], ls[NS];
#pragma unroll
  for (int sp = 0; sp < NS; ++sp) {
    if (sp * CHUNK < L) {
      float2 ml = *(const float2*)&pml[(base + (size_t)sp * Sn + q) * 2];
      ms[sp] = ml.x; ls[sp] = ml.y;
      M = fmaxf(M, ml.x);
      ns = sp + 1;
    }
  }
  float T = 0.f;
  float o[32];
#pragma unroll
  for (int d = 0; d < 32; ++d) o[d] = 0.f;
  for (int sp = 0; sp < ns; ++sp) {
    float w = __expf(ms[sp] - M);
    T += ls[sp] * w;
    const float4* pp = (const float4*)&pacc[(base + (size_t)sp * Sn + q) * 32];
#pragma unroll
    for (int i = 0; i < 8; ++i) {
      float4 v = pp[i];
      o[i * 4 + 0] = fmaf(w, v.x, o[i * 4 + 0]);
      o[i * 4 + 1] = fmaf(w, v.y, o[i * 4 + 1]);
      o[i * 4 + 2] = fmaf(w, v.z, o[i * 4 + 2]);
      o[i * 4 + 3] = fmaf(w, v.w, o[i * 4 + 3]);
    }
  }
  const float inv = 1.0f / T;
  _Float16* dst = &Ph[(size_t)b * Sn * En + (size_t)h * L * Dn + (size_t)q * Dn];
#pragma unroll
  for (int i = 0; i < 4; ++i) {
    half8_t hv;
#pragma unroll
    for (int t2 = 0; t2 < 8; ++t2) hv[t2] = (_Float16)(o[i * 8 + t2] * inv);
    *(half8_t*)&dst[i * 8] = hv;
  }
}

// ---------- zero Ph tail [L*E, S*E) per batch ----------
__global__ __launch_bounds__(256) void ztail_kernel(const int* __restrict__ len,
                                                    _Float16* __restrict__ Ph) {
  const int b = blockIdx.y;
  const int L = len[b];
  const int idx = (blockIdx.x * 256 + threadIdx.x) * 8;
  if (idx >= L * En) {
    half8_t z = {0, 0, 0, 0, 0, 0, 0, 0};
    *(half8_t*)&Ph[(size_t)b * Sn * En + idx] = z;
  }
}

extern "C" void kernel_launch(void* const* d_in, const int* in_sizes, int n_in,
                              void* d_out, int out_size, void* d_ws, size_t ws_size,
                              hipStream_t stream) {
  (void)in_sizes; (void)n_in; (void)out_size; (void)ws_size;
  const float* x  = (const float*)d_in[0];  // fp32 (B,S,E)
  const int* mask = (const int*)d_in[1];    // int32 (B,S)
  const float* Wq = (const float*)d_in[2];  // fp32 (E,E)
  const float* Wk = (const float*)d_in[3];
  const float* Wv = (const float*)d_in[4];
  const float* Wo = (const float*)d_in[5];
  float* out = (float*)d_out;               // fp32 (B,S,E)

  // ws: lengths | xh | Wh(Q|K|V|O) | Qh | Kh | Vt | Ph | pacc | pml  (~55 MB)
  float* wsf = (float*)d_ws;
  int* lengths = (int*)d_ws;
  const size_t BHSD = (size_t)Bn * Hn * Sn * Dn;  // 2,097,152
  _Float16* xh = (_Float16*)(wsf + 64);
  _Float16* Wh = xh + BHSD;                 // 4 x 65536
  _Float16* Qh = Wh + 4 * 65536;
  _Float16* Kh = Qh + BHSD;
  _Float16* Vt = Kh + BHSD;
  _Float16* Ph = Vt + BHSD;
  float* pacc = (float*)(Ph + BHSD);
  float* pml = pacc + (size_t)Bn * Hn * NS * Sn * 32;

  len_kernel<<<dim3(Bn), 256, 0, stream>>>(mask, lengths);
  cvt_kernel<<<dim3((2097152 + 262144) / (256 * 8)), 256, 0, stream>>>(
      x, Wq, Wk, Wv, Wo, xh, Wh);
  qkv_gemm<<<dim3(12, 32), 256, 0, stream>>>(xh, Wh, Qh, Kh, Vt);
  attn_kernel<<<dim3((Sn / 128) * NS, Hn, Bn), 256, 0, stream>>>(
      Qh, Kh, Vt, lengths, pacc, pml);
  combine_kernel<<<dim3(Sn / 256, Hn, Bn), 256, 0, stream>>>(
      pacc, pml, lengths, Ph);
  ztail_kernel<<<dim3(Sn * En / (256 * 8), Bn), 256, 0, stream>>>(lengths, Ph);
  out_gemm<<<dim3(4, 32), 256, 0, stream>>>(Ph, Wh + 3 * 65536, out);
}